// Round 8
// baseline (47.740 us; speedup 1.0000x reference)
//
#include <hip/hip_runtime.h>
#include <hip/hip_bf16.h>

// Problem constants (from reference)
#define B_   32
#define N_   64
#define C_   3
#define H_   512
#define W_   512
#define P_   16
#define PLANE (H_ * W_)          // 262144 floats per channel plane
#define IMG   (C_ * PLANE)       // 786432 floats per batch image

typedef float f32x4 __attribute__((ext_vector_type(4)));

// Wave-autonomous: one wave = ONE FULL ROW (512 cols) x 3 channels.
// lane covers 8 consecutive floats: 2 x f32x4 per channel = 6 independent
// loads + 6 nt stores = 96B streamed per thread. No LDS, no barriers.
// Each wave ballots the 64 patches of its image for row overlap and
// broadcasts the ~2 hits via one packed __shfl each (tr<<16|tc<<7|label).
// Loads CACHED (image is L3-resident across replays); stores NONTEMPORAL
// (out never re-read; don't evict image from L3).
__global__ __launch_bounds__(256)
void ImagePatch_fused_kernel(const float* __restrict__ image,
                             const float* __restrict__ emb,
                             const int*   __restrict__ labels,
                             const int*   __restrict__ top_left,
                             float*       __restrict__ out) {
    const int tid  = threadIdx.x;
    const int lane = tid & 63;
    const int gw   = blockIdx.x * 4 + (tid >> 6);   // global wave id = row id
    const int r    = gw & (H_ - 1);
    const int b    = gw >> 9;                       // / H_

    // ---- per-wave overlap list in registers ----
    const int idx = b * N_ + lane;
    const int tr  = top_left[idx * 2];
    const int tc  = top_left[idx * 2 + 1];
    const int lb  = labels[idx];
    const int pack = (tr << 16) | (tc << 7) | lb;
    unsigned long long m = __ballot((unsigned)(r - tr) < P_);

    // ---- stream: 6 loads up-front, add, 6 nt stores ----
    const int c0 = lane * 8;
    const size_t base = (size_t)b * IMG + (size_t)r * W_ + c0;

    f32x4 a0 = *(const f32x4*)(image + base);
    f32x4 b0 = *(const f32x4*)(image + base + 4);
    f32x4 a1 = *(const f32x4*)(image + base + PLANE);
    f32x4 b1 = *(const f32x4*)(image + base + PLANE + 4);
    f32x4 a2 = *(const f32x4*)(image + base + 2 * PLANE);
    f32x4 b2 = *(const f32x4*)(image + base + 2 * PLANE + 4);

    while (m) {
        const int k = __ffsll((unsigned long long)m) - 1;
        m &= m - 1;
        const int pk   = __shfl(pack, k);
        const int tr_k = pk >> 16;
        const int tc_k = (pk >> 7) & 0x1FF;
        const int lb_k = pk & 0x7F;
        const int dr   = r - tr_k;
        // does [c0, c0+8) intersect [tc_k, tc_k+16) ?
        if (c0 + 7 >= tc_k && c0 < tc_k + P_) {
            const float* e = emb + lb_k * (C_ * P_ * P_) + dr * P_;
            #pragma unroll
            for (int q = 0; q < 4; ++q) {
                const unsigned dca = (unsigned)(c0 + q - tc_k);
                const unsigned dcb = (unsigned)(c0 + 4 + q - tc_k);
                if (dca < P_) {
                    a0[q] += e[dca];
                    a1[q] += e[P_ * P_ + dca];
                    a2[q] += e[2 * P_ * P_ + dca];
                }
                if (dcb < P_) {
                    b0[q] += e[dcb];
                    b1[q] += e[P_ * P_ + dcb];
                    b2[q] += e[2 * P_ * P_ + dcb];
                }
            }
        }
    }

    __builtin_nontemporal_store(a0, (f32x4*)(out + base));
    __builtin_nontemporal_store(b0, (f32x4*)(out + base + 4));
    __builtin_nontemporal_store(a1, (f32x4*)(out + base + PLANE));
    __builtin_nontemporal_store(b1, (f32x4*)(out + base + PLANE + 4));
    __builtin_nontemporal_store(a2, (f32x4*)(out + base + 2 * PLANE));
    __builtin_nontemporal_store(b2, (f32x4*)(out + base + 2 * PLANE + 4));
}

extern "C" void kernel_launch(void* const* d_in, const int* in_sizes, int n_in,
                              void* d_out, int out_size, void* d_ws, size_t ws_size,
                              hipStream_t stream) {
    const float* image    = (const float*)d_in[0];   // [B, 3, H, W]
    const float* emb      = (const float*)d_in[1];   // [128, 768]
    const int*   labels   = (const int*)d_in[2];     // [B, N]
    const int*   top_left = (const int*)d_in[3];     // [B, N, 2]
    float*       out      = (float*)d_out;           // [B, 3, H, W]

    // one wave per row: B*H waves, 4 waves per 256-thread block
    const int grid = B_ * H_ / 4;                    // 4096 blocks
    ImagePatch_fused_kernel<<<grid, 256, 0, stream>>>(image, emb, labels, top_left, out);
}

// Round 9
// 36.410 us; speedup vs baseline: 1.3112x; 1.3112x over previous
//
#include <hip/hip_runtime.h>
#include <hip/hip_bf16.h>

// Problem constants (from reference)
#define B_   32
#define N_   64
#define C_   3
#define H_   512
#define W_   512
#define P_   16
#define PLANE (H_ * W_)          // 262144 floats per channel plane
#define IMG   (C_ * PLANE)       // 786432 floats per batch image

typedef float f32x4 __attribute__((ext_vector_type(4)));

// Wave-autonomous: one wave = ONE FULL ROW (512 cols) x 3 channels.
// Each lane owns two COALESCED f32x4 slots: cols [lane*4, lane*4+4) and
// [256+lane*4, 256+lane*4+4) -> every store instruction covers a solid
// 1KB wave segment (R8's interleaved 8-per-lane layout caused 26% HBM
// write amplification with nt-stores; this restores 98304KB writes).
// 6 independent loads up-front, register adds, 6 nt stores.
// Loads CACHED (image L3-resident across replays); stores NONTEMPORAL.
__global__ __launch_bounds__(256)
void ImagePatch_fused_kernel(const float* __restrict__ image,
                             const float* __restrict__ emb,
                             const int*   __restrict__ labels,
                             const int*   __restrict__ top_left,
                             float*       __restrict__ out) {
    const int tid  = threadIdx.x;
    const int lane = tid & 63;
    const int gw   = blockIdx.x * 4 + (tid >> 6);   // global wave id = row id
    const int r    = gw & (H_ - 1);
    const int b    = gw >> 9;                       // / H_

    // ---- per-wave overlap list in registers ----
    const int idx = b * N_ + lane;
    const int tr  = top_left[idx * 2];
    const int tc  = top_left[idx * 2 + 1];
    const int lb  = labels[idx];
    const int pack = (tr << 16) | (tc << 7) | lb;
    unsigned long long m = __ballot((unsigned)(r - tr) < P_);

    // ---- stream: 6 coalesced loads up-front ----
    const int ca = lane * 4;          // left half-row slot
    const int cb = 256 + lane * 4;    // right half-row slot
    const size_t ba = (size_t)b * IMG + (size_t)r * W_ + ca;
    const size_t bb = ba + 256;

    f32x4 a0 = *(const f32x4*)(image + ba);
    f32x4 a1 = *(const f32x4*)(image + ba + PLANE);
    f32x4 a2 = *(const f32x4*)(image + ba + 2 * PLANE);
    f32x4 b0 = *(const f32x4*)(image + bb);
    f32x4 b1 = *(const f32x4*)(image + bb + PLANE);
    f32x4 b2 = *(const f32x4*)(image + bb + 2 * PLANE);

    while (m) {
        const int k = __ffsll((unsigned long long)m) - 1;
        m &= m - 1;
        const int pk   = __shfl(pack, k);
        const int tr_k = pk >> 16;
        const int tc_k = (pk >> 7) & 0x1FF;
        const int lb_k = pk & 0x7F;
        const int dr   = r - tr_k;
        const float* e = emb + lb_k * (C_ * P_ * P_) + dr * P_;

        if (ca + 3 >= tc_k && ca < tc_k + P_) {     // left slot ∩ patch
            #pragma unroll
            for (int q = 0; q < 4; ++q) {
                const unsigned dc = (unsigned)(ca + q - tc_k);
                if (dc < P_) {
                    a0[q] += e[dc];
                    a1[q] += e[P_ * P_ + dc];
                    a2[q] += e[2 * P_ * P_ + dc];
                }
            }
        }
        if (cb + 3 >= tc_k && cb < tc_k + P_) {     // right slot ∩ patch
            #pragma unroll
            for (int q = 0; q < 4; ++q) {
                const unsigned dc = (unsigned)(cb + q - tc_k);
                if (dc < P_) {
                    b0[q] += e[dc];
                    b1[q] += e[P_ * P_ + dc];
                    b2[q] += e[2 * P_ * P_ + dc];
                }
            }
        }
    }

    __builtin_nontemporal_store(a0, (f32x4*)(out + ba));
    __builtin_nontemporal_store(a1, (f32x4*)(out + ba + PLANE));
    __builtin_nontemporal_store(a2, (f32x4*)(out + ba + 2 * PLANE));
    __builtin_nontemporal_store(b0, (f32x4*)(out + bb));
    __builtin_nontemporal_store(b1, (f32x4*)(out + bb + PLANE));
    __builtin_nontemporal_store(b2, (f32x4*)(out + bb + 2 * PLANE));
}

extern "C" void kernel_launch(void* const* d_in, const int* in_sizes, int n_in,
                              void* d_out, int out_size, void* d_ws, size_t ws_size,
                              hipStream_t stream) {
    const float* image    = (const float*)d_in[0];   // [B, 3, H, W]
    const float* emb      = (const float*)d_in[1];   // [128, 768]
    const int*   labels   = (const int*)d_in[2];     // [B, N]
    const int*   top_left = (const int*)d_in[3];     // [B, N, 2]
    float*       out      = (float*)d_out;           // [B, 3, H, W]

    // one wave per row: B*H waves, 4 waves per 256-thread block
    const int grid = B_ * H_ / 4;                    // 4096 blocks
    ImagePatch_fused_kernel<<<grid, 256, 0, stream>>>(image, emb, labels, top_left, out);
}

// Round 10
// 35.502 us; speedup vs baseline: 1.3447x; 1.0256x over previous
//
#include <hip/hip_runtime.h>
#include <hip/hip_bf16.h>

// Problem constants (from reference)
#define B_   32
#define N_   64
#define C_   3
#define H_   512
#define W_   512
#define P_   16
#define PLANE (H_ * W_)          // 262144 floats per channel plane
#define IMG   (C_ * PLANE)       // 786432 floats per batch image

typedef float f32x4 __attribute__((ext_vector_type(4)));

// BEST MEASURED (R7, 35.6us): wave-autonomous, one wave = half a row
// (256 cols) x 3 channels. No LDS, no __syncthreads. Each wave ballots the
// 64 patches of its image for row overlap and broadcasts the ~2 hits via
// one packed __shfl each (tr<<16 | tc<<7 | label). Then 3 up-front float4
// loads, register adds, 3 nt stores.
// Loads CACHED (image stays L3-resident across replays — profiled FETCH
// ~51MB of 100.7MB). Stores NONTEMPORAL (out never re-read; don't evict
// image from L3). Alternatives measured: cached stores 36.0us, full-row
// waves 36.4us, 16-row bands 88us, memcpy+scatter 44.3us.
__global__ __launch_bounds__(256)
void ImagePatch_fused_kernel(const float* __restrict__ image,
                             const float* __restrict__ emb,
                             const int*   __restrict__ labels,
                             const int*   __restrict__ top_left,
                             float*       __restrict__ out) {
    const int tid  = threadIdx.x;
    const int lane = tid & 63;
    const int gw   = blockIdx.x * 4 + (tid >> 6);   // global wave id
    const int half = gw & 1;
    const int r    = (gw >> 1) & (H_ - 1);
    const int b    = gw >> 10;                      // / (2*H_)

    // ---- per-wave overlap list in registers ----
    const int idx = b * N_ + lane;
    const int tr  = top_left[idx * 2];
    const int tc  = top_left[idx * 2 + 1];
    const int lb  = labels[idx];
    const int pack = (tr << 16) | (tc << 7) | lb;
    unsigned long long m = __ballot((unsigned)(r - tr) < P_);

    // ---- stream: 3 loads up-front, add, 3 stores ----
    const int c0 = lane * 4 + half * 256;
    const size_t base = (size_t)b * IMG + (size_t)r * W_ + c0;

    f32x4 v0 = *(const f32x4*)(image + base);
    f32x4 v1 = *(const f32x4*)(image + base + PLANE);
    f32x4 v2 = *(const f32x4*)(image + base + 2 * PLANE);

    while (m) {
        const int k = __ffsll((unsigned long long)m) - 1;
        m &= m - 1;
        const int pk   = __shfl(pack, k);
        const int tr_k = pk >> 16;
        const int tc_k = (pk >> 7) & 0x1FF;
        const int lb_k = pk & 0x7F;
        const int dr   = r - tr_k;
        if (c0 + 3 >= tc_k && c0 < tc_k + P_) {
            const float* e = emb + lb_k * (C_ * P_ * P_) + dr * P_;
            #pragma unroll
            for (int q = 0; q < 4; ++q) {
                const unsigned dc = (unsigned)(c0 + q - tc_k);
                if (dc < P_) {
                    v0[q] += e[dc];
                    v1[q] += e[P_ * P_ + dc];
                    v2[q] += e[2 * P_ * P_ + dc];
                }
            }
        }
    }

    __builtin_nontemporal_store(v0, (f32x4*)(out + base));
    __builtin_nontemporal_store(v1, (f32x4*)(out + base + PLANE));
    __builtin_nontemporal_store(v2, (f32x4*)(out + base + 2 * PLANE));
}

extern "C" void kernel_launch(void* const* d_in, const int* in_sizes, int n_in,
                              void* d_out, int out_size, void* d_ws, size_t ws_size,
                              hipStream_t stream) {
    const float* image    = (const float*)d_in[0];   // [B, 3, H, W]
    const float* emb      = (const float*)d_in[1];   // [128, 768]
    const int*   labels   = (const int*)d_in[2];     // [B, N]
    const int*   top_left = (const int*)d_in[3];     // [B, N, 2]
    float*       out      = (float*)d_out;           // [B, 3, H, W]

    // one wave per half-row: B * H * 2 waves, 4 waves per 256-thread block
    const int grid = B_ * H_ * 2 / 4;                // 8192 blocks
    ImagePatch_fused_kernel<<<grid, 256, 0, stream>>>(image, emb, labels, top_left, out);
}